// Round 3
// baseline (26.159 us; speedup 1.0000x reference)
//
#include <hip/hip_runtime.h>
#include <stdint.h>

#define I_DIM   256
#define O_DIM   256
#define B_ROWS  2048
#define KK      1024

typedef float f32x4 __attribute__((ext_vector_type(4)));
typedef short bf16x8 __attribute__((ext_vector_type(8)));

__device__ __forceinline__ uint32_t f2bf(float f) {
    uint32_t u = __builtin_bit_cast(uint32_t, f);
    u += 0x7fffu + ((u >> 16) & 1u);
    return u >> 16;
}

__device__ __forceinline__ float fast_tanh(float v) {
    float e = __expf(2.0f * v);
    return 1.0f - 2.0f / (e + 1.0f);
}

// T0..T3 of clip(tanh(v)) packed as 2x u32 (4 bf16, k ascending)
__device__ __forceinline__ void basis_words(float v, uint32_t& lo, uint32_t& hi) {
    const float CLIP = 0.99999994f;  // nextafter(1,0)
    float t = fast_tanh(v);
    t = fminf(CLIP, fmaxf(-CLIP, t));
    float t2 = __builtin_fmaf(2.0f * t, t, -1.0f);
    float t3 = __builtin_fmaf(2.0f * t, t2, -t);
    lo = 0x3f80u | (f2bf(t) << 16);     // T0=1.0, T1=t
    hi = f2bf(t2) | (f2bf(t3) << 16);   // T2, T3
}

// ---------------- K1: prep ----------------
// tasks [0, 262144):            A_bf16[2048][1024]  (one float2 of x -> 16B)
// tasks [262144, 327680):       Bt_bf16[256][1024]  (one (i,o) float4 -> 8B)
__global__ __launch_bounds__(256) void cheby_prep(
        const float* __restrict__ x, const float* __restrict__ cc,
        uint16_t* __restrict__ A, uint16_t* __restrict__ Bt) {
    const int task = blockIdx.x * 256 + threadIdx.x;
    if (task < 262144) {
        const int row = task >> 7;          // 0..2047
        const int h   = task & 127;         // which float2 within row
        float2 v = reinterpret_cast<const float2*>(x)[row * 128 + h];
        uint32_t l0, h0, l1, h1;
        basis_words(v.x, l0, h0);
        basis_words(v.y, l1, h1);
        *reinterpret_cast<uint4*>(reinterpret_cast<char*>(A) + row * 2048 + h * 16) =
            make_uint4(l0, h0, l1, h1);
    } else {
        const int t = task - 262144;
        const int i = t >> 8;               // 0..255
        const int o = t & 255;              // 0..255 (lanes walk o -> coalesced reads)
        float4 c = reinterpret_cast<const float4*>(cc)[i * 256 + o];
        uint32_t u0 = f2bf(c.x) | (f2bf(c.y) << 16);
        uint32_t u1 = f2bf(c.z) | (f2bf(c.w) << 16);
        *reinterpret_cast<uint2*>(reinterpret_cast<char*>(Bt) + o * 2048 + i * 8) =
            make_uint2(u0, u1);
    }
}

// ---------------- K2: register-streaming GEMM ----------------
// BM=BN=32, 4 waves per block, each wave one 16x16 quadrant over full K=1024.
// No LDS, no barriers: fragments loaded straight from L1/L2.
__global__ __launch_bounds__(256, 2) void cheby_gemm(
        const uint16_t* __restrict__ A, const uint16_t* __restrict__ Bt,
        float* __restrict__ out) {
    const int tid  = threadIdx.x;
    const int lane = tid & 63;
    const int wid  = tid >> 6;
    // bid = bn*64 + m  ->  XCD (bid%8) gets m%8: 512KB A-slice + full Bt, L2-resident
    const int m    = blockIdx.x & 63;
    const int bn   = blockIdx.x >> 6;
    const int m0   = m * 32;
    const int n0   = bn * 32;
    const int wr   = wid >> 1, wc = wid & 1;

    const int arow = m0 + wr * 16 + (lane & 15);
    const int bcol = n0 + wc * 16 + (lane & 15);
    const int koff = (lane >> 4) << 3;      // 0,8,16,24

    const uint16_t* ap = A  + arow * KK + koff;
    const uint16_t* bp = Bt + bcol * KK + koff;

    f32x4 acc0 = {0.f, 0.f, 0.f, 0.f};
    f32x4 acc1 = {0.f, 0.f, 0.f, 0.f};

    #pragma unroll
    for (int ks = 0; ks < 32; ks += 2) {
        bf16x8 a0 = *reinterpret_cast<const bf16x8*>(ap + ks * 32);
        bf16x8 b0 = *reinterpret_cast<const bf16x8*>(bp + ks * 32);
        bf16x8 a1 = *reinterpret_cast<const bf16x8*>(ap + ks * 32 + 32);
        bf16x8 b1 = *reinterpret_cast<const bf16x8*>(bp + ks * 32 + 32);
        acc0 = __builtin_amdgcn_mfma_f32_16x16x32_bf16(a0, b0, acc0, 0, 0, 0);
        acc1 = __builtin_amdgcn_mfma_f32_16x16x32_bf16(a1, b1, acc1, 0, 0, 0);
    }

    // C/D layout: col=lane&15, row=(lane>>4)*4+reg  [m89-verified, passed R1/R2]
    const float sc = 1.0f / 256.0f;
    f32x4 r = acc0 + acc1;
    const int gr = m0 + wr * 16 + ((lane >> 4) << 2);
    const int gc = n0 + wc * 16 + (lane & 15);
    #pragma unroll
    for (int q = 0; q < 4; ++q)
        out[(gr + q) * O_DIM + gc] = r[q] * sc;
}

// ---------------- fallback (R2 fused kernel) if ws too small ----------------
#define BM 32
#define BN 32
#define NCH 4
__global__ __launch_bounds__(256, 2) void cheby_fused(
        const float* __restrict__ x, const float* __restrict__ cc,
        float* __restrict__ out) {
    __shared__ __align__(16) unsigned char lds[65536];
    const int tid  = threadIdx.x;
    const int lane = tid & 63;
    const int wid  = tid >> 6;
    const int bm   = blockIdx.x >> 3;
    const int bn   = blockIdx.x & 7;
    const int m0   = bm * BM;
    const int n0   = bn * BN;
    const int arow = tid >> 3, aiq = tid & 7;
    const int bcl  = tid & 31, big = tid >> 5;
    const float4* x4 = reinterpret_cast<const float4*>(x);
    const float4* c4 = reinterpret_cast<const float4*>(cc);
    float4 ax0, ax1, cb[8];
    auto loadAB = [&](int ch) {
        const float4* p = &x4[(m0 + arow) * (I_DIM / 4) + ch * 16 + aiq * 2];
        ax0 = p[0]; ax1 = p[1];
        #pragma unroll
        for (int j = 0; j < 8; ++j) cb[j] = c4[(ch * 64 + big * 8 + j) * O_DIM + n0 + bcl];
    };
    auto stageAB = [&](int d) {
        const uint32_t abase = (uint32_t)(d * 16384 + arow * 512 + aiq * 64);
        const uint32_t axr   = (uint32_t)((arow & 31) << 4);
        uint32_t w0, w1, w2, w3, w4, w5, w6, w7;
        basis_words(ax0.x, w0, w1); basis_words(ax0.y, w2, w3);
        basis_words(ax0.z, w4, w5); basis_words(ax0.w, w6, w7);
        *reinterpret_cast<uint4*>(lds + ((abase     ) ^ axr)) = make_uint4(w0, w1, w2, w3);
        *reinterpret_cast<uint4*>(lds + ((abase + 16) ^ axr)) = make_uint4(w4, w5, w6, w7);
        basis_words(ax1.x, w0, w1); basis_words(ax1.y, w2, w3);
        basis_words(ax1.z, w4, w5); basis_words(ax1.w, w6, w7);
        *reinterpret_cast<uint4*>(lds + ((abase + 32) ^ axr)) = make_uint4(w0, w1, w2, w3);
        *reinterpret_cast<uint4*>(lds + ((abase + 48) ^ axr)) = make_uint4(w4, w5, w6, w7);
        const uint32_t bbase = (uint32_t)(32768 + d * 16384 + bcl * 512 + big * 64);
        const uint32_t bxr   = (uint32_t)((bcl & 31) << 4);
        #pragma unroll
        for (int j = 0; j < 8; j += 2) {
            uint32_t u0 = f2bf(cb[j].x)     | (f2bf(cb[j].y) << 16);
            uint32_t u1 = f2bf(cb[j].z)     | (f2bf(cb[j].w) << 16);
            uint32_t u2 = f2bf(cb[j + 1].x) | (f2bf(cb[j + 1].y) << 16);
            uint32_t u3 = f2bf(cb[j + 1].z) | (f2bf(cb[j + 1].w) << 16);
            *reinterpret_cast<uint4*>(lds + ((bbase + j * 8) ^ bxr)) = make_uint4(u0, u1, u2, u3);
        }
    };
    const int wr = wid >> 1, wc = wid & 1;
    const int mrow = wr * 16 + (lane & 15);
    const int bcol = wc * 16 + (lane & 15);
    const int klane = (lane >> 4) << 3;
    const uint32_t aswz = (uint32_t)((mrow & 31) << 4);
    const uint32_t bswz = (uint32_t)((bcol & 31) << 4);
    f32x4 acc0 = {0.f,0.f,0.f,0.f}, acc1 = {0.f,0.f,0.f,0.f};
    loadAB(0);
    #pragma unroll
    for (int ch = 0; ch < NCH; ++ch) {
        stageAB(ch & 1);
        if (ch + 1 < NCH) loadAB(ch + 1);
        __syncthreads();
        const uint32_t abase = (uint32_t)((ch & 1) * 16384 + mrow * 512);
        const uint32_t bbase = (uint32_t)(32768 + (ch & 1) * 16384 + bcol * 512);
        #pragma unroll
        for (int ks = 0; ks < 8; ++ks) {
            const uint32_t kb = (uint32_t)((ks * 32 + klane) * 2);
            bf16x8 a = *reinterpret_cast<const bf16x8*>(lds + ((abase + kb) ^ aswz));
            bf16x8 b = *reinterpret_cast<const bf16x8*>(lds + ((bbase + kb) ^ bswz));
            if (ks & 1) acc1 = __builtin_amdgcn_mfma_f32_16x16x32_bf16(a, b, acc1, 0, 0, 0);
            else        acc0 = __builtin_amdgcn_mfma_f32_16x16x32_bf16(a, b, acc0, 0, 0, 0);
        }
        if (ch + 1 < NCH) __syncthreads();
    }
    const float sc = 1.0f / 256.0f;
    f32x4 r = acc0 + acc1;
    const int gr = m0 + wr * 16 + ((lane >> 4) << 2);
    const int gc = n0 + wc * 16 + (lane & 15);
    #pragma unroll
    for (int q = 0; q < 4; ++q) out[(gr + q) * O_DIM + gc] = r[q] * sc;
}

extern "C" void kernel_launch(void* const* d_in, const int* in_sizes, int n_in,
                              void* d_out, int out_size, void* d_ws, size_t ws_size,
                              hipStream_t stream) {
    (void)in_sizes; (void)n_in; (void)out_size;
    const float* x  = (const float*)d_in[0];
    const float* cc = (const float*)d_in[1];
    float* out = (float*)d_out;
    const size_t needA  = (size_t)B_ROWS * KK * 2;          // 4 MiB
    const size_t needBt = (size_t)O_DIM * KK * 2;           // 512 KiB
    if (ws_size >= needA + needBt) {
        uint16_t* Abuf  = (uint16_t*)d_ws;
        uint16_t* Btbuf = (uint16_t*)((char*)d_ws + needA);
        cheby_prep<<<dim3(1280), dim3(256), 0, stream>>>(x, cc, Abuf, Btbuf);
        cheby_gemm<<<dim3(512), dim3(256), 0, stream>>>(Abuf, Btbuf, out);
    } else {
        cheby_fused<<<dim3(512), dim3(256), 0, stream>>>(x, cc, out);
    }
}

// Round 5
// 13.470 us; speedup vs baseline: 1.9420x; 1.9420x over previous
//
#include <hip/hip_runtime.h>
#include <hip/hip_bf16.h>
#include <stdint.h>

#define I_DIM   256
#define O_DIM   256
#define NCH     4      // K chunks: BK=256 (=64 i-values) each

typedef float f32x4 __attribute__((ext_vector_type(4)));
typedef short bf16x8 __attribute__((ext_vector_type(8)));

// pack 2 f32 -> u32 of 2 bf16 (RNE); compiler emits v_cvt_pk_bf16_f32
__device__ __forceinline__ uint32_t pk2(float a, float b) {
    __hip_bfloat162 h = __float22bfloat162_rn(make_float2(a, b));
    uint32_t u;
    __builtin_memcpy(&u, &h, 4);   // bit_cast rejected: type not trivially copyable
    return u;
}

// T0..T3 of clip(tanh(v)): lo = {T0=1, T1=t}, hi = {T2, T3}
__device__ __forceinline__ void basis2(float v, uint32_t& lo, uint32_t& hi) {
    const float CLIP = 0.99999994f;  // nextafter(1,0)
    float e = __expf(2.0f * v);
    float t = 1.0f - 2.0f / (e + 1.0f);
    t = fminf(CLIP, fmaxf(-CLIP, t));
    float t2 = __builtin_fmaf(2.0f * t, t, -1.0f);
    float t3 = __builtin_fmaf(2.0f * t, t2, -t);
    lo = pk2(1.0f, t);
    hi = pk2(t2, t3);
}

// LDS: A[s]: s*16384 + row*512 + kbyte ; B[s]: 32768 + s*16384 + col*512 + kbyte
// XOR-swizzled ^((row&31)<<4): frag reads 2-way (free), stage writes conflict-light
__global__ __launch_bounds__(256, 2) void cheby_mfma(
        const float* __restrict__ x, const float* __restrict__ cc,
        float* __restrict__ out) {
    __shared__ __align__(16) unsigned char lds[65536];

    const int tid  = threadIdx.x;
    const int lane = tid & 63;
    const int wid  = tid >> 6;
    const int bm   = blockIdx.x >> 3;   // 64 M-tiles
    const int bn   = blockIdx.x & 7;    // 8 N-tiles
    const int m0   = bm * 32;
    const int n0   = bn * 32;

    const int arow = tid >> 3;          // 0..31  A row
    const int aiq  = tid & 7;           // 0..7   pair of x-float4s
    const int bcl  = tid & 31;          // 0..31  B col
    const int big  = tid >> 5;          // 0..7   group of 8 i's

    const float4* __restrict__ x4 = reinterpret_cast<const float4*>(x);
    const float4* __restrict__ c4 = reinterpret_cast<const float4*>(cc);

    // two named prefetch register sets (parity); indices compile-time via full unroll
    float4 ax0[2], ax1[2], cb[2][8];

    auto loadAB = [&](int ch, int s) {
        const float4* p = &x4[(m0 + arow) * (I_DIM / 4) + ch * 16 + aiq * 2];
        ax0[s] = p[0]; ax1[s] = p[1];
        #pragma unroll
        for (int j = 0; j < 8; ++j)
            cb[s][j] = c4[(ch * 64 + big * 8 + j) * O_DIM + n0 + bcl];
    };

    auto stageAB = [&](int s) {
        const uint32_t abase = (uint32_t)(s * 16384 + arow * 512 + aiq * 64);
        const uint32_t axr   = (uint32_t)((arow & 31) << 4);
        uint32_t w0, w1, w2, w3, w4, w5, w6, w7;
        basis2(ax0[s].x, w0, w1); basis2(ax0[s].y, w2, w3);
        basis2(ax0[s].z, w4, w5); basis2(ax0[s].w, w6, w7);
        *reinterpret_cast<uint4*>(lds + ((abase     ) ^ axr)) = make_uint4(w0, w1, w2, w3);
        *reinterpret_cast<uint4*>(lds + ((abase + 16) ^ axr)) = make_uint4(w4, w5, w6, w7);
        basis2(ax1[s].x, w0, w1); basis2(ax1[s].y, w2, w3);
        basis2(ax1[s].z, w4, w5); basis2(ax1[s].w, w6, w7);
        *reinterpret_cast<uint4*>(lds + ((abase + 32) ^ axr)) = make_uint4(w0, w1, w2, w3);
        *reinterpret_cast<uint4*>(lds + ((abase + 48) ^ axr)) = make_uint4(w4, w5, w6, w7);
        const uint32_t bbase = (uint32_t)(32768 + s * 16384 + bcl * 512 + big * 64);
        const uint32_t bxr   = (uint32_t)((bcl & 31) << 4);
        #pragma unroll
        for (int j = 0; j < 8; j += 2) {
            uint32_t u0 = pk2(cb[s][j].x,     cb[s][j].y);
            uint32_t u1 = pk2(cb[s][j].z,     cb[s][j].w);
            uint32_t u2 = pk2(cb[s][j + 1].x, cb[s][j + 1].y);
            uint32_t u3 = pk2(cb[s][j + 1].z, cb[s][j + 1].w);
            *reinterpret_cast<uint4*>(lds + ((bbase + j * 8) ^ bxr)) = make_uint4(u0, u1, u2, u3);
        }
    };

    const int wr = wid >> 1, wc = wid & 1;
    const int mrow  = wr * 16 + (lane & 15);
    const int bcol  = wc * 16 + (lane & 15);
    const int klane = (lane >> 4) << 3;
    const uint32_t aswz = (uint32_t)((mrow & 31) << 4);
    const uint32_t bswz = (uint32_t)((bcol & 31) << 4);

    f32x4 acc0 = {0.f, 0.f, 0.f, 0.f};
    f32x4 acc1 = {0.f, 0.f, 0.f, 0.f};

    loadAB(0, 0);
    #pragma unroll
    for (int ch = 0; ch < NCH; ++ch) {
        const int s = ch & 1;
        if (ch + 1 < NCH) loadAB(ch + 1, s ^ 1);  // T14: issue loads BEFORE stage VALU
        stageAB(s);                               // stage VALU hides load latency
        __syncthreads();
        const uint32_t abase = (uint32_t)(s * 16384 + mrow * 512);
        const uint32_t bbase = (uint32_t)(32768 + s * 16384 + bcol * 512);
        #pragma unroll
        for (int ks = 0; ks < 8; ++ks) {
            const uint32_t kb = (uint32_t)((ks * 32 + klane) * 2);
            bf16x8 a = *reinterpret_cast<const bf16x8*>(lds + ((abase + kb) ^ aswz));
            bf16x8 b = *reinterpret_cast<const bf16x8*>(lds + ((bbase + kb) ^ bswz));
            if (ks & 1) acc1 = __builtin_amdgcn_mfma_f32_16x16x32_bf16(a, b, acc1, 0, 0, 0);
            else        acc0 = __builtin_amdgcn_mfma_f32_16x16x32_bf16(a, b, acc0, 0, 0, 0);
        }
        // one barrier per chunk suffices with double buffering (see R2 proof)
        if (ch + 1 < NCH) __syncthreads();
    }

    // C/D layout: col=lane&15, row=(lane>>4)*4+reg [m89-verified, passing since R1]
    const float sc = 1.0f / 256.0f;
    f32x4 r = acc0 + acc1;
    const int gr = m0 + wr * 16 + ((lane >> 4) << 2);
    const int gc = n0 + wc * 16 + (lane & 15);
    #pragma unroll
    for (int q = 0; q < 4; ++q)
        out[(gr + q) * O_DIM + gc] = r[q] * sc;
}

extern "C" void kernel_launch(void* const* d_in, const int* in_sizes, int n_in,
                              void* d_out, int out_size, void* d_ws, size_t ws_size,
                              hipStream_t stream) {
    (void)in_sizes; (void)n_in; (void)out_size; (void)d_ws; (void)ws_size;
    const float* x  = (const float*)d_in[0];
    const float* cc = (const float*)d_in[1];
    float* out = (float*)d_out;
    // single kernel (two-kernel graphs cost ~+10us): 512 blocks, 4 waves, 2 blk/CU
    cheby_mfma<<<dim3(512), dim3(256), 0, stream>>>(x, cc, out);
}